// Round 3
// baseline (104.763 us; speedup 1.0000x reference)
//
#include <hip/hip_runtime.h>

// Fused no-softmax attention block, MI355X/gfx950.
// out = LN( q + Q @ Gt_b^T + bo ),  Q = q@Wq^T+bq,
// Gt_b[n,k'] = sum_d Wo[n,h(k')*64+d] * M_bh[d',d]/8,  M_bh = K^T V  (no softmax -> associativity exact)
// GEMM structure: 128x128 tile, 2-phase dbuf LDS via global_load_lds(16B),
// quad-XOR swizzle slot = k16 ^ (row&3) ^ ((row>>2)&3)  (32-bank conflict-free per 8-lane phase).
// proj: 2 waves/block, per-wave 128x64 = 8x4 frags (43.7 FLOP/LDS-byte).

typedef __bf16 bf16;
typedef __bf16 bf16x8 __attribute__((ext_vector_type(8)));
typedef float f32x4 __attribute__((ext_vector_type(4)));

#define MFMA16(a, b, c) __builtin_amdgcn_mfma_f32_16x16x32_bf16(a, b, c, 0, 0, 0)

__device__ __forceinline__ bf16x8 ld8(const bf16* p) { return *(const bf16x8*)p; }

__device__ __forceinline__ void gload16(const void* g, void* l) {
  __builtin_amdgcn_global_load_lds((__attribute__((address_space(1))) void*)(g),
                                   (__attribute__((address_space(3))) void*)(l), 16, 0, 0);
}

// ---------------- 1. f32 -> bf16: q,k,v (2048 blk each), Wq,Wk,Wv (512 blk each) ----------------
__global__ __launch_bounds__(256) void cvt_kernel(
    const float* __restrict__ q, const float* __restrict__ k, const float* __restrict__ v,
    const float* __restrict__ wq, const float* __restrict__ wk, const float* __restrict__ wv,
    bf16* __restrict__ dst) {
  const int bid = blockIdx.x;
  const float* s; size_t dof; int x;
  if (bid < 6144) {
    const int y = bid >> 11; x = bid & 2047;
    s = (y == 0) ? q : (y == 1 ? k : v);
    dof = (size_t)y * 4194304u;
  } else {
    const int idx = bid - 6144; const int y = idx >> 9; x = idx & 511;
    s = (y == 0) ? wq : (y == 1 ? wk : wv);
    dof = 12582912u + (size_t)y * 1048576u;
  }
  const size_t i = ((size_t)x * 256 + threadIdx.x) * 8;
  f32x4 a = *(const f32x4*)(s + i);
  f32x4 b = *(const f32x4*)(s + i + 4);
  bf16x8 o;
  o[0] = (bf16)a[0]; o[1] = (bf16)a[1]; o[2] = (bf16)a[2]; o[3] = (bf16)a[3];
  o[4] = (bf16)b[0]; o[5] = (bf16)b[1]; o[6] = (bf16)b[2]; o[7] = (bf16)b[3];
  *(bf16x8*)(dst + dof + i) = o;
}

// ---------------- 2. QKV proj: C = A @ W^T + bias. 128x128, 2 waves, 8x4 frags/wave ----------------
__global__ __launch_bounds__(128, 2) void gemm_proj_f(
    const bf16* __restrict__ Aall, const bf16* __restrict__ Wall,
    const float* __restrict__ bq, const float* __restrict__ bk, const float* __restrict__ bv,
    bf16* __restrict__ Call) {
  __shared__ __align__(128) char lds[32768];  // 2 bufs x (A 8KB + B 8KB)
  const int z = blockIdx.y;
  const int wg = blockIdx.x;
  const int swz = ((wg & 7) << 5) + (wg >> 3);   // XCD-chunked, 256%8==0 bijective
  const int n0 = (swz & 7) * 128, m0 = (swz >> 3) * 128;
  const bf16* A = Aall + (size_t)z * 4194304u;
  const bf16* W = Wall + (size_t)z * 1048576u;
  const float* bias = (z == 0) ? bq : (z == 1 ? bk : bv);
  bf16* C = Call + (size_t)z * 4194304u;

  const int t = threadIdx.x;
  const int l = t & 63, wid = t >> 6;
  const int r16 = l & 15, kg = l >> 4;
  const int wbase = wid << 10;

  // staging: slot(p*128+t) holds chunk (row = p*32 + t/4, c = (t&3)^(row&3)^((row>>2)&3))
  const bf16* ap[4]; const bf16* bp[4]; int adst[4], bdst[4];
#pragma unroll
  for (int p = 0; p < 4; p++) {
    const int row = p * 32 + (t >> 2);
    const int c = (t & 3) ^ (row & 3) ^ ((row >> 2) & 3);
    ap[p] = A + (size_t)(m0 + row) * 1024 + c * 8;
    bp[p] = W + (size_t)(n0 + row) * 1024 + c * 8;
    adst[p] = p * 2048 + wbase;
    bdst[p] = 8192 + p * 2048 + wbase;
  }
  // read offsets (swizzled)
  int aoff[8], boff[4];
#pragma unroll
  for (int i = 0; i < 8; i++) {
    const int row = i * 16 + r16;
    aoff[i] = row * 64 + ((kg ^ (row & 3) ^ ((row >> 2) & 3)) << 4);
  }
#pragma unroll
  for (int j = 0; j < 4; j++) {
    const int row = wid * 64 + j * 16 + r16;
    boff[j] = 8192 + row * 64 + ((kg ^ (row & 3) ^ ((row >> 2) & 3)) << 4);
  }

  f32x4 acc[8][4] = {};
#pragma unroll
  for (int p = 0; p < 4; p++) { gload16(ap[p], lds + adst[p]); gload16(bp[p], lds + bdst[p]); }
  __syncthreads();

  int buf = 0;
  for (int kt = 0; kt < 32; kt++) {
    if (kt < 31) {
      char* d = lds + ((buf ^ 1) << 14);
#pragma unroll
      for (int p = 0; p < 4; p++) {
        gload16(ap[p] + (kt + 1) * 32, d + adst[p]);
        gload16(bp[p] + (kt + 1) * 32, d + bdst[p]);
      }
    }
    const char* lb = lds + (buf << 14);
    bf16x8 bv_[4];
#pragma unroll
    for (int j = 0; j < 4; j++) bv_[j] = *(const bf16x8*)(lb + boff[j]);
#pragma unroll
    for (int i = 0; i < 8; i++) {
      bf16x8 av = *(const bf16x8*)(lb + aoff[i]);
#pragma unroll
      for (int j = 0; j < 4; j++) acc[i][j] = MFMA16(av, bv_[j], acc[i][j]);
    }
    __syncthreads();
    buf ^= 1;
  }

#pragma unroll
  for (int j = 0; j < 4; j++) {
    const int col = n0 + wid * 64 + j * 16 + r16;
    const float bj = bias[col];
#pragma unroll
    for (int i = 0; i < 8; i++) {
      const int row = m0 + i * 16 + kg * 4;   // C/D: col=lane&15, row=(lane>>4)*4+r
#pragma unroll
      for (int r = 0; r < 4; r++)
        C[(size_t)(row + r) * 1024 + col] = (bf16)(acc[i][j][r] + bj);
    }
  }
}

// ---------------- shared 4-wave 128x128 loop (for gemm_out), quad-XOR swizzle ----------------
__device__ __forceinline__ void gemm_loop(const bf16* __restrict__ A,
                                          const bf16* __restrict__ Bw,
                                          int m0, int n0, char* lds, f32x4 acc[4][4]) {
  const int t = threadIdx.x;
  const int l = t & 63, w = t >> 6;
  const int wr = w >> 1, wc = w & 1;
  const int r16 = l & 15, kg = l >> 4;
  const int sw = ((kg ^ (r16 & 3) ^ ((r16 >> 2) & 3)) << 4);
  const int aoff = wr * 4096 + r16 * 64 + sw;          // + i*1024
  const int boff = 8192 + wc * 4096 + r16 * 64 + sw;   // + j*1024

  const int srow = t >> 2;
  const int k16 = (t & 3) ^ (srow & 3) ^ ((srow >> 2) & 3);  // same for srow+64
  const bf16* gA = A + (size_t)(m0 + srow) * 1024 + k16 * 8;
  const bf16* gB = Bw + (size_t)(n0 + srow) * 1024 + k16 * 8;
  const int wbase = (t >> 6) << 10;

  gload16(gA, lds + wbase);
  gload16(gA + 65536, lds + 4096 + wbase);
  gload16(gB, lds + 8192 + wbase);
  gload16(gB + 65536, lds + 12288 + wbase);
  __syncthreads();

  int buf = 0;
  for (int kt = 0; kt < 32; kt++) {
    if (kt < 31) {
      const bf16* ga = gA + (kt + 1) * 32;
      const bf16* gb = gB + (kt + 1) * 32;
      char* dst = lds + ((buf ^ 1) << 14) + wbase;
      gload16(ga, dst);
      gload16(ga + 65536, dst + 4096);
      gload16(gb, dst + 8192);
      gload16(gb + 65536, dst + 12288);
    }
    const char* la = lds + (buf << 14) + aoff;
    const char* lb = lds + (buf << 14) + boff;
    bf16x8 av[4], bv[4];
#pragma unroll
    for (int i = 0; i < 4; i++) av[i] = *(const bf16x8*)(la + i * 1024);
#pragma unroll
    for (int j = 0; j < 4; j++) bv[j] = *(const bf16x8*)(lb + j * 1024);
#pragma unroll
    for (int i = 0; i < 4; i++)
#pragma unroll
      for (int j = 0; j < 4; j++) acc[i][j] = MFMA16(av[i], bv[j], acc[i][j]);
    __syncthreads();
    buf ^= 1;
  }
}

// ---------------- 3. M[b,h][i][j] += sum_s K[s,i] * V[s,j] ----------------
__global__ __launch_bounds__(256) void ktv_kernel(
    const bf16* __restrict__ Kb, const bf16* __restrict__ Vb, float* __restrict__ M) {
  const int bh = blockIdx.y, b = bh >> 4, h = bh & 15;
  const int s0 = blockIdx.x * 128;
  __shared__ bf16 Kl[64][136];
  __shared__ bf16 Vl[64][136];
  const int t = threadIdx.x;
  const size_t base = ((size_t)b * 2048 + s0) * 1024 + h * 64;
#pragma unroll
  for (int p = 0; p < 4; p++) {
    const int chunk = p * 256 + t;
    const int s = chunk >> 3, d0 = (chunk & 7) * 8;
    bf16x8 kv = ld8(Kb + base + (size_t)s * 1024 + d0);
    bf16x8 vv = ld8(Vb + base + (size_t)s * 1024 + d0);
#pragma unroll
    for (int e = 0; e < 8; e++) { Kl[d0 + e][s] = kv[e]; Vl[d0 + e][s] = vv[e]; }
  }
  __syncthreads();
  const int l = t & 63, w = t >> 6;
  const int r16 = l & 15, kg = l >> 4;
  f32x4 acc[4] = {};
#pragma unroll
  for (int ks = 0; ks < 4; ks++) {
    bf16x8 a = ld8(&Kl[w * 16 + r16][ks * 32 + kg * 8]);
#pragma unroll
    for (int j = 0; j < 4; j++) {
      bf16x8 bvv = ld8(&Vl[j * 16 + r16][ks * 32 + kg * 8]);
      acc[j] = MFMA16(a, bvv, acc[j]);
    }
  }
  float* Mh = M + (size_t)bh * 4096;
#pragma unroll
  for (int j = 0; j < 4; j++)
#pragma unroll
    for (int r = 0; r < 4; r++)
      atomicAdd(&Mh[(w * 16 + kg * 4 + r) * 64 + j * 16 + r16], acc[j][r]);
}

// ---------------- 4. Gt[b][n][h*64+d'] = sum_d Wo[n,h*64+d](f32) * M_bh[d',d]/8 ----------------
__global__ __launch_bounds__(256) void gt_kernel(
    const float* __restrict__ Wo, const float* __restrict__ M, bf16* __restrict__ Gt) {
  const int bid = blockIdx.x;
  const int b = bid >> 7, h = (bid >> 3) & 15, nt = bid & 7;
  const int n0 = nt * 128;
  const float* Mh = M + (size_t)((b << 4) + h) * 4096;
  const int l = threadIdx.x & 63, w = threadIdx.x >> 6;
  const int r16 = l & 15, kg = l >> 4;
  f32x4 acc[2][4] = {};
#pragma unroll
  for (int kk = 0; kk < 2; kk++) {
    bf16x8 a[2];
#pragma unroll
    for (int i = 0; i < 2; i++) {
      const float* wp = Wo + (size_t)(n0 + w * 32 + i * 16 + r16) * 1024 + h * 64 + kk * 32 + kg * 8;
      f32x4 lo = *(const f32x4*)wp;
      f32x4 hi = *(const f32x4*)(wp + 4);
      a[i][0] = (bf16)lo[0]; a[i][1] = (bf16)lo[1]; a[i][2] = (bf16)lo[2]; a[i][3] = (bf16)lo[3];
      a[i][4] = (bf16)hi[0]; a[i][5] = (bf16)hi[1]; a[i][6] = (bf16)hi[2]; a[i][7] = (bf16)hi[3];
    }
#pragma unroll
    for (int j = 0; j < 4; j++) {
      const float* mp = Mh + (j * 16 + r16) * 64 + kk * 32 + kg * 8;
      f32x4 m0v = *(const f32x4*)mp;
      f32x4 m1v = *(const f32x4*)(mp + 4);
      bf16x8 bv;
      bv[0] = (bf16)(m0v[0] * 0.125f); bv[1] = (bf16)(m0v[1] * 0.125f);
      bv[2] = (bf16)(m0v[2] * 0.125f); bv[3] = (bf16)(m0v[3] * 0.125f);
      bv[4] = (bf16)(m1v[0] * 0.125f); bv[5] = (bf16)(m1v[1] * 0.125f);
      bv[6] = (bf16)(m1v[2] * 0.125f); bv[7] = (bf16)(m1v[3] * 0.125f);
#pragma unroll
      for (int i = 0; i < 2; i++) acc[i][j] = MFMA16(a[i], bv, acc[i][j]);
    }
  }
  bf16* G = Gt + (size_t)b * 1048576u;
#pragma unroll
  for (int i = 0; i < 2; i++)
#pragma unroll
    for (int j = 0; j < 4; j++)
#pragma unroll
      for (int r = 0; r < 4; r++)
        G[(size_t)(n0 + w * 32 + i * 16 + kg * 4 + r) * 1024 + h * 64 + j * 16 + r16] =
            (bf16)acc[i][j][r];
}

// ---------------- 5. out = resid + Q @ Gt_b^T + bo  (f32) ----------------
__global__ __launch_bounds__(256) void gemm_out(
    const bf16* __restrict__ Q, const bf16* __restrict__ Gt,
    const float* __restrict__ bo, const float* __restrict__ resid, float* __restrict__ out) {
  __shared__ __align__(128) char lds[32768];
  const int wg = blockIdx.x;
  const int swz = ((wg & 7) << 5) + (wg >> 3);
  const int n0 = (swz & 7) * 128, m0 = (swz >> 3) * 128;
  const bf16* B = Gt + (size_t)(m0 >> 11) * 1048576u;  // per-batch G

  f32x4 acc[4][4] = {};
  gemm_loop(Q, B, m0, n0, lds, acc);

  const int l = threadIdx.x & 63, w = threadIdx.x >> 6;
  const int wr = w >> 1, wc = w & 1, r16 = l & 15, kg = l >> 4;
#pragma unroll
  for (int j = 0; j < 4; j++) {
    const int col = n0 + wc * 64 + j * 16 + r16;
    const float bj = bo[col];
#pragma unroll
    for (int i = 0; i < 4; i++) {
      const int row = m0 + wr * 64 + i * 16 + kg * 4;
#pragma unroll
      for (int r = 0; r < 4; r++) {
        const size_t off = (size_t)(row + r) * 1024 + col;
        out[off] = acc[i][j][r] + bj + resid[off];
      }
    }
  }
}

// ---------------- 6. LayerNorm: one row per wave, shfl-only reduce ----------------
__global__ __launch_bounds__(256) void ln_kernel(
    float* __restrict__ x, const float* __restrict__ g, const float* __restrict__ bb) {
  const int lane = threadIdx.x & 63, wid = threadIdx.x >> 6;
  const int row = (blockIdx.x << 2) + wid;
  float* xr = x + (size_t)row * 1024;
  f32x4 v[4];
  float s = 0.f, s2 = 0.f;
#pragma unroll
  for (int e = 0; e < 4; e++) {
    v[e] = *(const f32x4*)(xr + lane * 16 + e * 4);
#pragma unroll
    for (int u = 0; u < 4; u++) { s += v[e][u]; s2 += v[e][u] * v[e][u]; }
  }
#pragma unroll
  for (int m = 32; m; m >>= 1) { s += __shfl_xor(s, m); s2 += __shfl_xor(s2, m); }
  const float mu = s * (1.0f / 1024.0f);
  const float rstd = rsqrtf(s2 * (1.0f / 1024.0f) - mu * mu + 1e-5f);
#pragma unroll
  for (int e = 0; e < 4; e++) {
    f32x4 gg = *(const f32x4*)(g + lane * 16 + e * 4);
    f32x4 bv = *(const f32x4*)(bb + lane * 16 + e * 4);
    f32x4 o;
#pragma unroll
    for (int u = 0; u < 4; u++) o[u] = gg[u] * ((v[e][u] - mu) * rstd) + bv[u];
    *(f32x4*)(xr + lane * 16 + e * 4) = o;
  }
}

extern "C" void kernel_launch(void* const* d_in, const int* in_sizes, int n_in,
                              void* d_out, int out_size, void* d_ws, size_t ws_size,
                              hipStream_t stream) {
  (void)in_sizes; (void)n_in; (void)out_size; (void)ws_size;
  const float* q    = (const float*)d_in[0];
  const float* k    = (const float*)d_in[1];
  const float* v    = (const float*)d_in[2];
  // d_in[3]=mask (all False), d_in[4]=training: unused
  const float* wq_w = (const float*)d_in[5];
  const float* wq_b = (const float*)d_in[6];
  const float* wk_w = (const float*)d_in[7];
  const float* wk_b = (const float*)d_in[8];
  const float* wv_w = (const float*)d_in[9];
  const float* wv_b = (const float*)d_in[10];
  const float* wo_w = (const float*)d_in[11];
  const float* wo_b = (const float*)d_in[12];
  const float* ln_g = (const float*)d_in[13];
  const float* ln_b = (const float*)d_in[14];
  float* out = (float*)d_out;

  bf16* wsb    = (bf16*)d_ws;
  bf16* qkv_bf = wsb;                       // [0, 24MB) q,k,v bf16 (dead after gemm_proj_f)
  bf16* w_bf   = wsb + 12582912u;           // Wq,Wk,Wv bf16 (3M elems)
  bf16* QKV_bf = wsb + 15728640u;           // Q,K,V bf16 (12M elems)
  float* M     = (float*)wsb;               // alias dead q region: 256K f32
  bf16* Gt     = wsb + 524288u;             // alias dead q region: 2M elems

  cvt_kernel<<<7680, 256, 0, stream>>>(q, k, v, wq_w, wk_w, wv_w, wsb);
  gemm_proj_f<<<dim3(256, 3), 128, 0, stream>>>(qkv_bf, w_bf, wq_b, wk_b, wv_b, QKV_bf);
  hipMemsetAsync(M, 0, 32 * 64 * 64 * sizeof(float), stream);
  ktv_kernel<<<dim3(16, 32), 256, 0, stream>>>(QKV_bf + 4194304u, QKV_bf + 8388608u, M);
  gt_kernel<<<256, 256, 0, stream>>>(wo_w, M, Gt);
  gemm_out<<<256, 256, 0, stream>>>(QKV_bf, Gt, wo_b, q, out);
  ln_kernel<<<1024, 256, 0, stream>>>(out, ln_g, ln_b);
}

// Round 4
// 96.237 us; speedup vs baseline: 1.0886x; 1.0886x over previous
//
#include <hip/hip_runtime.h>

// Fused no-softmax attention block, MI355X/gfx950.
// out = LN( q + Q @ Gt_b^T + bo ),  Q = q@Wq^T+bq,
// Gt_b[n,k'] = sum_d Wo[n,h(k')*64+d] * M_bh[d',d]/8,  M_bh = K^T V  (no softmax -> exact)
// GEMMs: 128x128 tile, BK=32, ring-3 LDS (48KB) + counted s_waitcnt vmcnt(4) + raw s_barrier
// (loads never drained to 0 in the loop), setprio(1) around MFMA, quad-XOR LDS swizzle,
// XCD-chunked grid. M zeroed by cvt (no hipMemsetAsync - it cost 40us as fillBufferAligned).

typedef __bf16 bf16;
typedef __bf16 bf16x8 __attribute__((ext_vector_type(8)));
typedef float f32x4 __attribute__((ext_vector_type(4)));

#define MFMA16(a, b, c) __builtin_amdgcn_mfma_f32_16x16x32_bf16(a, b, c, 0, 0, 0)
#define VMCNT(n) asm volatile("s_waitcnt vmcnt(" #n ")" ::: "memory")
#define BARRIER() asm volatile("s_barrier" ::: "memory")

__device__ __forceinline__ bf16x8 ld8(const bf16* p) { return *(const bf16x8*)p; }

__device__ __forceinline__ void gload16(const void* g, void* l) {
  __builtin_amdgcn_global_load_lds((__attribute__((address_space(1))) void*)(g),
                                   (__attribute__((address_space(3))) void*)(l), 16, 0, 0);
}

__device__ __forceinline__ int swz_slot(int row, int c) {
  return c ^ (row & 3) ^ ((row >> 2) & 3);
}

// ---------------- 1. f32 -> bf16 (q,k,v,Wq,Wk,Wv) + zero M ----------------
__global__ __launch_bounds__(256) void cvt_kernel(
    const float* __restrict__ q, const float* __restrict__ k, const float* __restrict__ v,
    const float* __restrict__ wq, const float* __restrict__ wk, const float* __restrict__ wv,
    bf16* __restrict__ dst, float* __restrict__ Mz) {
  const int bid = blockIdx.x;
  if (bid >= 7680) {  // zero M: 64 blocks x 256 thr x 8 f32 = 131072 f32
    float* p = Mz + (size_t)(bid - 7680) * 2048 + threadIdx.x * 8;
    *(f32x4*)p = f32x4{0.f, 0.f, 0.f, 0.f};
    *(f32x4*)(p + 4) = f32x4{0.f, 0.f, 0.f, 0.f};
    return;
  }
  const float* s; size_t dof; int x;
  if (bid < 6144) {
    const int y = bid >> 11; x = bid & 2047;
    s = (y == 0) ? q : (y == 1 ? k : v);
    dof = (size_t)y * 4194304u;
  } else {
    const int idx = bid - 6144; const int y = idx >> 9; x = idx & 511;
    s = (y == 0) ? wq : (y == 1 ? wk : wv);
    dof = 12582912u + (size_t)y * 1048576u;
  }
  const size_t i = ((size_t)x * 256 + threadIdx.x) * 8;
  f32x4 a = *(const f32x4*)(s + i);
  f32x4 b = *(const f32x4*)(s + i + 4);
  bf16x8 o;
  o[0] = (bf16)a[0]; o[1] = (bf16)a[1]; o[2] = (bf16)a[2]; o[3] = (bf16)a[3];
  o[4] = (bf16)b[0]; o[5] = (bf16)b[1]; o[6] = (bf16)b[2]; o[7] = (bf16)b[3];
  *(bf16x8*)(dst + dof + i) = o;
}

// ---------------- ring-3 GEMM mainloop: 128x128 tile, K=1024, BK=32 ----------------
// 256 thr = 4 waves (2x2), wave tile 64x64 (4x4 16x16 frags).
// LDS buf = A[128][32] (8KB) + B[128][32] (8KB), 3 bufs. Stage 4 x gload16/thread/tile.
// Steady state: 2 tiles in flight; VMCNT(4) guarantees current tile landed.
__device__ __forceinline__ void compute16(const char* buf, const int aoff[4], const int boff[4],
                                          f32x4 (&acc)[4][4]) {
  bf16x8 av[4], bv[4];
#pragma unroll
  for (int i = 0; i < 4; i++) av[i] = *(const bf16x8*)(buf + aoff[i]);
#pragma unroll
  for (int j = 0; j < 4; j++) bv[j] = *(const bf16x8*)(buf + boff[j]);
  __builtin_amdgcn_s_setprio(1);
#pragma unroll
  for (int i = 0; i < 4; i++)
#pragma unroll
    for (int j = 0; j < 4; j++) acc[i][j] = MFMA16(av[i], bv[j], acc[i][j]);
  __builtin_amdgcn_s_setprio(0);
}

__device__ __forceinline__ void ring128(const bf16* __restrict__ A, const bf16* __restrict__ B,
                                        char* lds, f32x4 (&acc)[4][4]) {
  const int t = threadIdx.x;
  const int lane = t & 63, wid = t >> 6;
  const int wr = wid >> 1, wc = wid & 1;
  const int r16 = lane & 15, kg = lane >> 4;

  int aoff[4], boff[4];
#pragma unroll
  for (int i = 0; i < 4; i++) {
    int row = wr * 64 + i * 16 + r16;
    aoff[i] = row * 64 + (swz_slot(row, kg) << 4);
    row = wc * 64 + i * 16 + r16;
    boff[i] = 8192 + row * 64 + (swz_slot(row, kg) << 4);
  }

  // staging map: thread t -> chunk t (row r1=t>>2) and chunk t+256 (row r2=r1+64);
  // LDS linear dest; global source pre-swizzled (slot holds chunk c^s(row)).
  const int r1 = t >> 2, c = t & 3, r2 = r1 + 64;
  const bf16* pa1 = A + (size_t)r1 * 1024 + swz_slot(r1, c) * 8;
  const bf16* pa2 = A + (size_t)r2 * 1024 + swz_slot(r2, c) * 8;
  const bf16* pb1 = B + (size_t)r1 * 1024 + swz_slot(r1, c) * 8;
  const bf16* pb2 = B + (size_t)r2 * 1024 + swz_slot(r2, c) * 8;
  const int d1 = wid << 10, d2 = 4096 + (wid << 10);

  // prologue: tiles 0,1 -> bufs 0,1 (8 loads in flight)
#pragma unroll
  for (int p = 0; p < 2; p++) {
    char* d = lds + p * 16384;
    gload16(pa1 + p * 32, d + d1);
    gload16(pa2 + p * 32, d + d2);
    gload16(pb1 + p * 32, d + 8192 + d1);
    gload16(pb2 + p * 32, d + 8192 + d2);
  }
  pa1 += 64; pa2 += 64; pb1 += 64; pb2 += 64;

  int cb = 0, rb = 2;
  for (int kt = 0; kt < 30; kt++) {
    VMCNT(4);    // tile kt landed; kt+1 (and soon kt+2) stay in flight
    BARRIER();   // raw: no compiler vmcnt(0) drain; all waves' tile-kt loads visible
    {
      char* d = lds + rb * 16384;
      gload16(pa1, d + d1);
      gload16(pa2, d + d2);
      gload16(pb1, d + 8192 + d1);
      gload16(pb2, d + 8192 + d2);
      pa1 += 32; pa2 += 32; pb1 += 32; pb2 += 32;
    }
    compute16(lds + cb * 16384, aoff, boff, acc);
    cb = (cb == 2) ? 0 : cb + 1;
    rb = (rb == 2) ? 0 : rb + 1;
  }
  VMCNT(4); BARRIER(); compute16(lds + cb * 16384, aoff, boff, acc);  // kt=30
  cb = (cb == 2) ? 0 : cb + 1;
  VMCNT(0); BARRIER(); compute16(lds + cb * 16384, aoff, boff, acc);  // kt=31
}

// ---------------- 2. QKV proj: C = A @ W^T + bias (bf16), rows 0..12287 span z ----------------
__global__ __launch_bounds__(256, 3) void gemm_proj_r(
    const bf16* __restrict__ qkv, const bf16* __restrict__ Wall,
    const float* __restrict__ bq, const float* __restrict__ bk, const float* __restrict__ bv,
    bf16* __restrict__ Call) {
  __shared__ __align__(1024) char lds[49152];
  const int wg = blockIdx.x;                   // 768 = 96 mt x 8 nt
  const int swz = (wg & 7) * 96 + (wg >> 3);   // XCD-chunked, bijective (768%8==0)
  const int mt = swz >> 3, nt = swz & 7;
  const int m0 = mt * 128, n0 = nt * 128;
  const int z = m0 >> 12;

  f32x4 acc[4][4] = {};
  ring128(qkv + (size_t)m0 * 1024, Wall + (size_t)z * 1048576u + (size_t)n0 * 1024, lds, acc);

  const float* bias = (z == 0) ? bq : (z == 1 ? bk : bv);
  const int lane = threadIdx.x & 63, wid = threadIdx.x >> 6;
  const int wr = wid >> 1, wc = wid & 1, r16 = lane & 15, kg = lane >> 4;
#pragma unroll
  for (int j = 0; j < 4; j++) {
    const int col = n0 + wc * 64 + j * 16 + r16;
    const float bj = bias[col];
#pragma unroll
    for (int i = 0; i < 4; i++) {
      const int row = m0 + wr * 64 + i * 16 + kg * 4;
#pragma unroll
      for (int r = 0; r < 4; r++)
        Call[(size_t)(row + r) * 1024 + col] = (bf16)(acc[i][j][r] + bj);
    }
  }
}

// ---------------- 3. M[b,h][i][j] += sum_s K[s,i] * V[s,j] ----------------
__global__ __launch_bounds__(256) void ktv_kernel(
    const bf16* __restrict__ Kb, const bf16* __restrict__ Vb, float* __restrict__ M) {
  const int bh = blockIdx.y, b = bh >> 4, h = bh & 15;
  const int s0 = blockIdx.x * 128;
  __shared__ bf16 Kl[64][136];
  __shared__ bf16 Vl[64][136];
  const int t = threadIdx.x;
  const size_t base = ((size_t)b * 2048 + s0) * 1024 + h * 64;
#pragma unroll
  for (int p = 0; p < 4; p++) {
    const int chunk = p * 256 + t;
    const int s = chunk >> 3, d0 = (chunk & 7) * 8;
    bf16x8 kv = ld8(Kb + base + (size_t)s * 1024 + d0);
    bf16x8 vv = ld8(Vb + base + (size_t)s * 1024 + d0);
#pragma unroll
    for (int e = 0; e < 8; e++) { Kl[d0 + e][s] = kv[e]; Vl[d0 + e][s] = vv[e]; }
  }
  __syncthreads();
  const int l = t & 63, w = t >> 6;
  const int r16 = l & 15, kg = l >> 4;
  f32x4 acc[4] = {};
#pragma unroll
  for (int ks = 0; ks < 4; ks++) {
    bf16x8 a = ld8(&Kl[w * 16 + r16][ks * 32 + kg * 8]);
#pragma unroll
    for (int j = 0; j < 4; j++) {
      bf16x8 bvv = ld8(&Vl[j * 16 + r16][ks * 32 + kg * 8]);
      acc[j] = MFMA16(a, bvv, acc[j]);
    }
  }
  float* Mh = M + (size_t)bh * 4096;
#pragma unroll
  for (int j = 0; j < 4; j++)
#pragma unroll
    for (int r = 0; r < 4; r++)
      atomicAdd(&Mh[(w * 16 + kg * 4 + r) * 64 + j * 16 + r16], acc[j][r]);
}

// ---------------- 4. Gt[b][n][h*64+d'] = sum_d Wo[n,h*64+d](f32) * M_bh[d',d]/8 ----------------
__global__ __launch_bounds__(256) void gt_kernel(
    const float* __restrict__ Wo, const float* __restrict__ M, bf16* __restrict__ Gt) {
  const int bid = blockIdx.x;
  const int b = bid >> 7, h = (bid >> 3) & 15, nt = bid & 7;
  const int n0 = nt * 128;
  const float* Mh = M + (size_t)((b << 4) + h) * 4096;
  const int l = threadIdx.x & 63, w = threadIdx.x >> 6;
  const int r16 = l & 15, kg = l >> 4;
  f32x4 acc[2][4] = {};
#pragma unroll
  for (int kk = 0; kk < 2; kk++) {
    bf16x8 a[2];
#pragma unroll
    for (int i = 0; i < 2; i++) {
      const float* wp = Wo + (size_t)(n0 + w * 32 + i * 16 + r16) * 1024 + h * 64 + kk * 32 + kg * 8;
      f32x4 lo = *(const f32x4*)wp;
      f32x4 hi = *(const f32x4*)(wp + 4);
      a[i][0] = (bf16)lo[0]; a[i][1] = (bf16)lo[1]; a[i][2] = (bf16)lo[2]; a[i][3] = (bf16)lo[3];
      a[i][4] = (bf16)hi[0]; a[i][5] = (bf16)hi[1]; a[i][6] = (bf16)hi[2]; a[i][7] = (bf16)hi[3];
    }
#pragma unroll
    for (int j = 0; j < 4; j++) {
      const float* mp = Mh + (j * 16 + r16) * 64 + kk * 32 + kg * 8;
      f32x4 m0v = *(const f32x4*)mp;
      f32x4 m1v = *(const f32x4*)(mp + 4);
      bf16x8 bv;
      bv[0] = (bf16)(m0v[0] * 0.125f); bv[1] = (bf16)(m0v[1] * 0.125f);
      bv[2] = (bf16)(m0v[2] * 0.125f); bv[3] = (bf16)(m0v[3] * 0.125f);
      bv[4] = (bf16)(m1v[0] * 0.125f); bv[5] = (bf16)(m1v[1] * 0.125f);
      bv[6] = (bf16)(m1v[2] * 0.125f); bv[7] = (bf16)(m1v[3] * 0.125f);
#pragma unroll
      for (int i = 0; i < 2; i++) acc[i][j] = MFMA16(a[i], bv, acc[i][j]);
    }
  }
  bf16* G = Gt + (size_t)b * 1048576u;
#pragma unroll
  for (int i = 0; i < 2; i++)
#pragma unroll
    for (int j = 0; j < 4; j++)
#pragma unroll
      for (int r = 0; r < 4; r++)
        G[(size_t)(n0 + w * 32 + i * 16 + kg * 4 + r) * 1024 + h * 64 + j * 16 + r16] =
            (bf16)acc[i][j][r];
}

// ---------------- 5. out = resid + Q @ Gt_b^T + bo (f32) ----------------
__global__ __launch_bounds__(256, 3) void gemm_out_r(
    const bf16* __restrict__ Q, const bf16* __restrict__ Gt,
    const float* __restrict__ bo, const float* __restrict__ resid, float* __restrict__ out) {
  __shared__ __align__(1024) char lds[49152];
  const int wg = blockIdx.x;                   // 256 = 32 mt x 8 nt
  const int swz = (wg & 7) * 32 + (wg >> 3);
  const int mt = swz >> 3, nt = swz & 7;
  const int m0 = mt * 128, n0 = nt * 128;

  f32x4 acc[4][4] = {};
  ring128(Q + (size_t)m0 * 1024, Gt + (size_t)(m0 >> 11) * 1048576u + (size_t)n0 * 1024, lds, acc);

  const int lane = threadIdx.x & 63, wid = threadIdx.x >> 6;
  const int wr = wid >> 1, wc = wid & 1, r16 = lane & 15, kg = lane >> 4;
#pragma unroll
  for (int j = 0; j < 4; j++) {
    const int col = n0 + wc * 64 + j * 16 + r16;
    const float bj = bo[col];
#pragma unroll
    for (int i = 0; i < 4; i++) {
      const int row = m0 + wr * 64 + i * 16 + kg * 4;
#pragma unroll
      for (int r = 0; r < 4; r++) {
        const size_t off = (size_t)(row + r) * 1024 + col;
        out[off] = acc[i][j][r] + bj + resid[off];
      }
    }
  }
}

// ---------------- 6. LayerNorm: one row per wave, shfl-only reduce ----------------
__global__ __launch_bounds__(256) void ln_kernel(
    float* __restrict__ x, const float* __restrict__ g, const float* __restrict__ bb) {
  const int lane = threadIdx.x & 63, wid = threadIdx.x >> 6;
  const int row = (blockIdx.x << 2) + wid;
  float* xr = x + (size_t)row * 1024;
  f32x4 v[4];
  float s = 0.f, s2 = 0.f;
#pragma unroll
  for (int e = 0; e < 4; e++) {
    v[e] = *(const f32x4*)(xr + lane * 16 + e * 4);
#pragma unroll
    for (int u = 0; u < 4; u++) { s += v[e][u]; s2 += v[e][u] * v[e][u]; }
  }
#pragma unroll
  for (int m = 32; m; m >>= 1) { s += __shfl_xor(s, m); s2 += __shfl_xor(s2, m); }
  const float mu = s * (1.0f / 1024.0f);
  const float rstd = rsqrtf(s2 * (1.0f / 1024.0f) - mu * mu + 1e-5f);
#pragma unroll
  for (int e = 0; e < 4; e++) {
    f32x4 gg = *(const f32x4*)(g + lane * 16 + e * 4);
    f32x4 bv = *(const f32x4*)(bb + lane * 16 + e * 4);
    f32x4 o;
#pragma unroll
    for (int u = 0; u < 4; u++) o[u] = gg[u] * ((v[e][u] - mu) * rstd) + bv[u];
    *(f32x4*)(xr + lane * 16 + e * 4) = o;
  }
}

extern "C" void kernel_launch(void* const* d_in, const int* in_sizes, int n_in,
                              void* d_out, int out_size, void* d_ws, size_t ws_size,
                              hipStream_t stream) {
  (void)in_sizes; (void)n_in; (void)out_size; (void)ws_size;
  const float* q    = (const float*)d_in[0];
  const float* k    = (const float*)d_in[1];
  const float* v    = (const float*)d_in[2];
  // d_in[3]=mask (all False), d_in[4]=training: unused
  const float* wq_w = (const float*)d_in[5];
  const float* wq_b = (const float*)d_in[6];
  const float* wk_w = (const float*)d_in[7];
  const float* wk_b = (const float*)d_in[8];
  const float* wv_w = (const float*)d_in[9];
  const float* wv_b = (const float*)d_in[10];
  const float* wo_w = (const float*)d_in[11];
  const float* wo_b = (const float*)d_in[12];
  const float* ln_g = (const float*)d_in[13];
  const float* ln_b = (const float*)d_in[14];
  float* out = (float*)d_out;

  bf16* wsb    = (bf16*)d_ws;
  bf16* qkv_bf = wsb;                        // [0 .. 12582912) q,k,v bf16 (dead after proj)
  bf16* w_bf   = wsb + 12582912u;            // Wq,Wk,Wv bf16 (3,145,728 elems)
  bf16* QKV_bf = wsb + 15728640u;            // Q,K,V bf16 (12,582,912 elems)
  float* M     = (float*)(wsb + 28311552u);  // fresh region: 131072 f32 (512 KiB)
  bf16* Gt     = wsb;                        // alias dead q region: 2,097,152 elems

  cvt_kernel<<<7744, 256, 0, stream>>>(q, k, v, wq_w, wk_w, wv_w, qkv_bf, M);
  gemm_proj_r<<<768, 256, 0, stream>>>(qkv_bf, w_bf, wq_b, wk_b, wv_b, QKV_bf);
  ktv_kernel<<<dim3(16, 32), 256, 0, stream>>>(QKV_bf + 4194304u, QKV_bf + 8388608u, M);
  gt_kernel<<<256, 256, 0, stream>>>(wo_w, M, Gt);
  gemm_out_r<<<256, 256, 0, stream>>>(QKV_bf, Gt, wo_b, q, out);
  ln_kernel<<<1024, 256, 0, stream>>>(out, ln_g, ln_b);
}